// Round 1
// baseline (585.785 us; speedup 1.0000x reference)
//
#include <hip/hip_runtime.h>
#include <cstdint>
#include <cstddef>

#define NVARS 2048
#define DG    256
#define NSLOT 8
#define NN2   (NVARS*NVARS)
#define K_SEL 2097152u
#define EQ_CAP 8192
#define TS 128
#define KC 32

// ---------------- static device scratch (no d_ws dependence) ----------------
__device__ float    g_nv[NSLOT][2][NVARS*DG];    // nv1/nv2 per slot
__device__ unsigned g_hist[NSLOT][2048];
__device__ unsigned g_eqbuf[NSLOT][EQ_CAP];
__device__ unsigned g_state[NSLOT][16];
// state: 0 primary, 1 first_occ, 2 prefix, 3 k_rem, 4 t_u, 5 count_eq,
//        6 num_eq_keep, 7 cutoff_idx, 8 eq_count, 9 need_eq
__device__ float    g_scal[2];                   // [0]=(1-prop), [1]=prop

__device__ __forceinline__ unsigned fkey(float x){
  unsigned b = __float_as_uint(x);
  return (b & 0x80000000u) ? ~b : (b | 0x80000000u);
}

// ---------------- prep: schedule scalar, dedup flags, zero hists ------------
__global__ __launch_bounds__(256) void k_prep(const int* __restrict__ tind,
                                              const int* __restrict__ epoch_p){
  int tid = threadIdx.x;
  if (tid < NSLOT){
    int t = tind[tid];
    int fo = tid;
    for (int b = 0; b < tid; b++){ if (tind[b] == t){ fo = b; break; } }
    g_state[tid][0] = (fo == tid) ? 1u : 0u;
    g_state[tid][1] = (unsigned)fo;
    g_state[tid][2] = 0u;
    g_state[tid][3] = K_SEL;
    g_state[tid][4] = 0u;
    g_state[tid][5] = 0u;
    g_state[tid][6] = 0u;
    g_state[tid][7] = 0x7FFFFFFFu;
    g_state[tid][8] = 0u;
    g_state[tid][9] = 0u;
  }
  if (tid == 0){
    double pd = (double)epoch_p[0] / 5.0;
    if (pd > 0.9) pd = 0.9;
    g_scal[0] = (float)(1.0 - pd);
    g_scal[1] = (float)pd;
  }
  unsigned* h = (unsigned*)g_hist;
  for (int i = tid; i < NSLOT*2048; i += 256) h[i] = 0u;
}

// ---------------- GEMM1: nv = tanh(E @ W^T + b), per (slot, which) ----------
__global__ __launch_bounds__(256) void k_gemm_nv(
    const float* __restrict__ emb1, const float* __restrict__ emb2,
    const float* __restrict__ w1,  const float* __restrict__ b1,
    const float* __restrict__ w2,  const float* __restrict__ b2,
    const int* __restrict__ tind){
  int z = blockIdx.z; int s = z >> 1; int w = z & 1;
  if (!g_state[s][0]) return;
  int t = tind[s];
  const float* E    = (w ? emb2 : emb1) + (size_t)t*NVARS*DG;
  const float* W    = (w ? w2 : w1)     + (size_t)t*DG*DG;
  const float* bias = (w ? b2 : b1)     + (size_t)t*DG;
  float* outp = g_nv[s][w];
  int rowBase = blockIdx.y*TS, colBase = blockIdx.x*TS;
  __shared__ float At[KC][TS];
  __shared__ float Bt[KC][TS];
  int tid = threadIdx.x, tx = tid & 15, ty = tid >> 4;
  float acc[8][8] = {};
  for (int k0 = 0; k0 < DG; k0 += KC){
    for (int f = tid; f < TS*KC/4; f += 256){
      int rr = f >> 3, kq = f & 7;
      float4 v = *(const float4*)(E + (size_t)(rowBase+rr)*DG + k0 + kq*4);
      At[kq*4+0][rr]=v.x; At[kq*4+1][rr]=v.y; At[kq*4+2][rr]=v.z; At[kq*4+3][rr]=v.w;
    }
    for (int f = tid; f < TS*KC/4; f += 256){
      int rr = f >> 3, kq = f & 7;
      float4 v = *(const float4*)(W + (size_t)(colBase+rr)*DG + k0 + kq*4);
      Bt[kq*4+0][rr]=v.x; Bt[kq*4+1][rr]=v.y; Bt[kq*4+2][rr]=v.z; Bt[kq*4+3][rr]=v.w;
    }
    __syncthreads();
    #pragma unroll 4
    for (int kk = 0; kk < KC; kk++){
      float a[8], b[8];
      *(float4*)&a[0] = *(const float4*)&At[kk][ty*8];
      *(float4*)&a[4] = *(const float4*)&At[kk][ty*8+4];
      *(float4*)&b[0] = *(const float4*)&Bt[kk][tx*8];
      *(float4*)&b[4] = *(const float4*)&Bt[kk][tx*8+4];
      #pragma unroll
      for (int i = 0; i < 8; i++)
        #pragma unroll
        for (int j = 0; j < 8; j++) acc[i][j] += a[i]*b[j];
    }
    __syncthreads();
  }
  for (int i = 0; i < 8; i++){
    int r = rowBase + ty*8 + i;
    float o[8];
    #pragma unroll
    for (int j = 0; j < 8; j++){
      int c = colBase + tx*8 + j;
      o[j] = tanhf(acc[i][j] + bias[c]);
    }
    *(float4*)(outp + (size_t)r*DG + colBase + tx*8)     = *(float4*)&o[0];
    *(float4*)(outp + (size_t)r*DG + colBase + tx*8 + 4) = *(float4*)&o[4];
  }
}

// ---------------- GEMM2: a = (1-p)*init + p*(nv1@nv2^T), diag=-inf ----------
__global__ __launch_bounds__(256) void k_gemm_s(const float* __restrict__ init,
                                                float* __restrict__ out){
  int s = blockIdx.z;
  if (!g_state[s][0]) return;
  const float* A = g_nv[s][0];
  const float* B = g_nv[s][1];
  float am1 = g_scal[0], am2 = g_scal[1];
  int rowBase = blockIdx.y*TS, colBase = blockIdx.x*TS;
  __shared__ float At[KC][TS];
  __shared__ float Bt[KC][TS];
  int tid = threadIdx.x, tx = tid & 15, ty = tid >> 4;
  float acc[8][8] = {};
  for (int k0 = 0; k0 < DG; k0 += KC){
    for (int f = tid; f < TS*KC/4; f += 256){
      int rr = f >> 3, kq = f & 7;
      float4 v = *(const float4*)(A + (size_t)(rowBase+rr)*DG + k0 + kq*4);
      At[kq*4+0][rr]=v.x; At[kq*4+1][rr]=v.y; At[kq*4+2][rr]=v.z; At[kq*4+3][rr]=v.w;
    }
    for (int f = tid; f < TS*KC/4; f += 256){
      int rr = f >> 3, kq = f & 7;
      float4 v = *(const float4*)(B + (size_t)(colBase+rr)*DG + k0 + kq*4);
      Bt[kq*4+0][rr]=v.x; Bt[kq*4+1][rr]=v.y; Bt[kq*4+2][rr]=v.z; Bt[kq*4+3][rr]=v.w;
    }
    __syncthreads();
    #pragma unroll 4
    for (int kk = 0; kk < KC; kk++){
      float a[8], b[8];
      *(float4*)&a[0] = *(const float4*)&At[kk][ty*8];
      *(float4*)&a[4] = *(const float4*)&At[kk][ty*8+4];
      *(float4*)&b[0] = *(const float4*)&Bt[kk][tx*8];
      *(float4*)&b[4] = *(const float4*)&Bt[kk][tx*8+4];
      #pragma unroll
      for (int i = 0; i < 8; i++)
        #pragma unroll
        for (int j = 0; j < 8; j++) acc[i][j] += a[i]*b[j];
    }
    __syncthreads();
  }
  float* outs = out + (size_t)s*NN2;
  for (int i = 0; i < 8; i++){
    int r = rowBase + ty*8 + i;
    const float* irow = init + (size_t)r*NVARS + colBase + tx*8;
    float4 i0 = *(const float4*)irow;
    float4 i1 = *(const float4*)(irow + 4);
    float iv[8] = {i0.x,i0.y,i0.z,i0.w,i1.x,i1.y,i1.z,i1.w};
    float o[8];
    #pragma unroll
    for (int j = 0; j < 8; j++){
      int c = colBase + tx*8 + j;
      float val = am1*iv[j] + am2*acc[i][j];
      o[j] = (c == r) ? -__builtin_inff() : val;
    }
    *(float4*)(outs + (size_t)r*NVARS + colBase + tx*8)     = *(float4*)&o[0];
    *(float4*)(outs + (size_t)r*NVARS + colBase + tx*8 + 4) = *(float4*)&o[4];
  }
}

// ---------------- radix-select histogram passes -----------------------------
__global__ __launch_bounds__(256) void k_hist(const float* __restrict__ out, int pass){
  int s = blockIdx.z;
  if (!g_state[s][0]) return;
  __shared__ unsigned h[2048];
  int tid = threadIdx.x;
  for (int i = tid; i < 2048; i += 256) h[i] = 0u;
  __syncthreads();
  unsigned prefix = g_state[s][2];
  const float4* p = (const float4*)(out + (size_t)s*NN2);
  int stride = gridDim.x*256;
  for (int i = blockIdx.x*256 + tid; i < NN2/4; i += stride){
    float4 v = p[i];
    float xs[4] = {v.x, v.y, v.z, v.w};
    #pragma unroll
    for (int j = 0; j < 4; j++){
      unsigned u = fkey(xs[j]);
      if (pass == 1)      atomicAdd(&h[u >> 21], 1u);
      else if (pass == 2){ if ((u >> 21) == (prefix >> 21)) atomicAdd(&h[(u >> 10) & 0x7FFu], 1u); }
      else               { if ((u >> 10) == (prefix >> 10)) atomicAdd(&h[u & 0x3FFu], 1u); }
    }
  }
  __syncthreads();
  for (int i = tid; i < 2048; i += 256){
    unsigned c = h[i];
    if (c) atomicAdd(&g_hist[s][i], c);
  }
}

// ---------------- select the digit for rank k_rem (descending) --------------
__global__ __launch_bounds__(256) void k_select(int pass){
  int s = blockIdx.x;
  if (!g_state[s][0]) return;
  int tid = threadIdx.x;
  int nb  = (pass == 3) ? 1024 : 2048;
  int per = nb >> 8;
  __shared__ unsigned scan[256];
  unsigned loc[8];
  unsigned own = 0;
  int base = tid*per;
  for (int j = 0; j < per; j++){ loc[j] = g_hist[s][base+j]; own += loc[j]; }
  scan[tid] = own;
  __syncthreads();
  for (int off = 1; off < 256; off <<= 1){
    unsigned v = (tid + off < 256) ? scan[tid+off] : 0u;
    __syncthreads();
    scan[tid] += v;
    __syncthreads();
  }
  unsigned krem = g_state[s][3];
  unsigned acc = scan[tid] - own;  // counts in strictly higher threads
  int found = -1; unsigned accAbove = 0, cnt = 0;
  for (int j = per-1; j >= 0; j--){
    unsigned c = loc[j];
    if (c && krem > acc && krem <= acc + c){ found = base+j; accAbove = acc; cnt = c; }
    acc += c;
  }
  if (found >= 0){
    if (pass == 1){ g_state[s][2] = ((unsigned)found) << 21; g_state[s][3] = krem - accAbove; }
    else if (pass == 2){ g_state[s][2] |= ((unsigned)found) << 10; g_state[s][3] = krem - accAbove; }
    else {
      unsigned tu  = g_state[s][2] | (unsigned)found;
      unsigned nek = krem - accAbove;
      g_state[s][4] = tu;
      g_state[s][5] = cnt;
      g_state[s][6] = nek;
      g_state[s][7] = 0x7FFFFFFFu;
      g_state[s][8] = 0u;
      g_state[s][9] = (nek < cnt) ? 1u : 0u;
    }
  }
  __syncthreads();
  for (int i = tid; i < 2048; i += 256) g_hist[s][i] = 0u;
}

// ---------------- rare path: collect indices equal to threshold -------------
__global__ __launch_bounds__(256) void k_eqcollect(const float* __restrict__ out){
  int s = blockIdx.z;
  if (!g_state[s][0] || !g_state[s][9]) return;
  unsigned tu = g_state[s][4];
  const float4* p = (const float4*)(out + (size_t)s*NN2);
  int tid = threadIdx.x;
  int stride = gridDim.x*256;
  for (int i = blockIdx.x*256 + tid; i < NN2/4; i += stride){
    float4 v = p[i];
    float xs[4] = {v.x, v.y, v.z, v.w};
    #pragma unroll
    for (int j = 0; j < 4; j++){
      if (fkey(xs[j]) == tu){
        unsigned pos = atomicAdd(&g_state[s][8], 1u);
        if (pos < EQ_CAP) g_eqbuf[s][pos] = (unsigned)(i*4 + j);
      }
    }
  }
}

// ---------------- rare path: cutoff = num_eq_keep-th smallest index ---------
__global__ __launch_bounds__(256) void k_eqsel(){
  int s = blockIdx.x;
  if (!g_state[s][0] || !g_state[s][9]) return;
  int tid = threadIdx.x;
  unsigned total = g_state[s][8];
  if (total > EQ_CAP){ if (tid == 0) g_state[s][7] = 0x7FFFFFFFu; return; }
  unsigned m = total;
  unsigned nek = g_state[s][6];
  __shared__ unsigned h[2048];
  __shared__ unsigned scan[256];
  __shared__ unsigned sh_digit, sh_j;
  for (int i = tid; i < 2048; i += 256) h[i] = 0u;
  __syncthreads();
  for (unsigned i = tid; i < m; i += 256) atomicAdd(&h[g_eqbuf[s][i] >> 11], 1u);
  __syncthreads();
  {
    unsigned loc[8]; unsigned own = 0; int base = tid*8;
    for (int j = 0; j < 8; j++){ loc[j] = h[base+j]; own += loc[j]; }
    scan[tid] = own; __syncthreads();
    for (int off = 1; off < 256; off <<= 1){
      unsigned v = (tid >= off) ? scan[tid-off] : 0u;
      __syncthreads(); scan[tid] += v; __syncthreads();
    }
    unsigned below = scan[tid] - own;
    for (int j = 0; j < 8; j++){
      unsigned c = loc[j];
      if (c && nek > below && nek <= below + c){ sh_digit = (unsigned)(base+j); sh_j = nek - below; }
      below += c;
    }
  }
  __syncthreads();
  unsigned dh = sh_digit, j2 = sh_j;
  for (int i = tid; i < 2048; i += 256) h[i] = 0u;
  __syncthreads();
  for (unsigned i = tid; i < m; i += 256){
    unsigned v = g_eqbuf[s][i];
    if ((v >> 11) == dh) atomicAdd(&h[v & 0x7FFu], 1u);
  }
  __syncthreads();
  {
    unsigned loc[8]; unsigned own = 0; int base = tid*8;
    for (int j = 0; j < 8; j++){ loc[j] = h[base+j]; own += loc[j]; }
    scan[tid] = own; __syncthreads();
    for (int off = 1; off < 256; off <<= 1){
      unsigned v = (tid >= off) ? scan[tid-off] : 0u;
      __syncthreads(); scan[tid] += v; __syncthreads();
    }
    unsigned below = scan[tid] - own;
    for (int j = 0; j < 8; j++){
      unsigned c = loc[j];
      if (c && j2 > below && j2 <= below + c) g_state[s][7] = (dh << 11) | (unsigned)(base+j);
      below += c;
    }
  }
}

// ---------------- mask + tanh/relu + eye + row-normalize (in place) ---------
__global__ __launch_bounds__(256) void k_masknorm(float* __restrict__ out){
  int s = blockIdx.y;
  if (!g_state[s][0]) return;
  int r = blockIdx.x;
  int tid = threadIdx.x;
  unsigned tu = g_state[s][4];
  unsigned cutoff = g_state[s][7];
  float* row = out + (size_t)s*NN2 + (size_t)r*NVARS;
  __shared__ float vals[NVARS];
  __shared__ double red[256];
  double lsum = 0.0;
  for (int c = tid; c < NVARS; c += 256){
    float v;
    if (c == r) v = 1.0f;
    else {
      float a = row[c];
      unsigned u = fkey(a);
      bool keep = (u > tu) || (u == tu && (unsigned)(r*NVARS + c) <= cutoff);
      v = keep ? fmaxf(tanhf(a), 0.0f) : 0.0f;
    }
    vals[c] = v;
    lsum += (double)v;
  }
  red[tid] = lsum;
  __syncthreads();
  for (int off = 128; off > 0; off >>= 1){
    if (tid < off) red[tid] += red[tid+off];
    __syncthreads();
  }
  float inv = 1.0f / (float)red[0];
  for (int c = tid; c < NVARS; c += 256) row[c] = vals[c] * inv;
}

// ---------------- duplicate slots: copy from first occurrence ---------------
__global__ __launch_bounds__(256) void k_dedup(float* __restrict__ out){
  int s = blockIdx.z;
  if (g_state[s][0]) return;
  int fo = (int)g_state[s][1];
  const float4* src = (const float4*)(out + (size_t)fo*NN2);
  float4* dst = (float4*)(out + (size_t)s*NN2);
  int stride = gridDim.x*256;
  for (int i = blockIdx.x*256 + threadIdx.x; i < NN2/4; i += stride) dst[i] = src[i];
}

// ---------------- host launcher ---------------------------------------------
extern "C" void kernel_launch(void* const* d_in, const int* in_sizes, int n_in,
                              void* d_out, int out_size, void* d_ws, size_t ws_size,
                              hipStream_t stream){
  (void)in_sizes; (void)n_in; (void)d_ws; (void)ws_size; (void)out_size;
  const float* init = (const float*)d_in[0];
  const float* emb1 = (const float*)d_in[1];
  const float* emb2 = (const float*)d_in[2];
  const float* w1   = (const float*)d_in[3];
  const float* b1   = (const float*)d_in[4];
  const float* w2   = (const float*)d_in[5];
  const float* b2   = (const float*)d_in[6];
  const int* tind   = (const int*)d_in[7];
  const int* epoch  = (const int*)d_in[8];
  float* out = (float*)d_out;

  k_prep<<<1, 256, 0, stream>>>(tind, epoch);
  k_gemm_nv<<<dim3(2, 16, 16), 256, 0, stream>>>(emb1, emb2, w1, b1, w2, b2, tind);
  k_gemm_s<<<dim3(16, 16, 8), 256, 0, stream>>>(init, out);
  for (int pass = 1; pass <= 3; pass++){
    k_hist<<<dim3(256, 1, 8), 256, 0, stream>>>(out, pass);
    k_select<<<8, 256, 0, stream>>>(pass);
  }
  k_eqcollect<<<dim3(256, 1, 8), 256, 0, stream>>>(out);
  k_eqsel<<<8, 256, 0, stream>>>();
  k_masknorm<<<dim3(2048, 8), 256, 0, stream>>>(out);
  k_dedup<<<dim3(128, 1, 8), 256, 0, stream>>>(out);
}

// Round 2
// 500.036 us; speedup vs baseline: 1.1715x; 1.1715x over previous
//
#include <hip/hip_runtime.h>
#include <cstdint>
#include <cstddef>

#define NVARS 2048
#define DG    256
#define NSLOT 8
#define NN2   (NVARS*NVARS)
#define K_SEL 2097152u
#define CAP   (1u<<18)
#define TS 128
#define KC 32
#define TSP (TS+4)
#define KBIG 768

typedef __attribute__((ext_vector_type(8))) short short8;
typedef __attribute__((ext_vector_type(8))) unsigned short ushort8;
typedef __attribute__((ext_vector_type(4))) float floatx4;

// ---------------- static device scratch ----------------
__device__ __align__(16) unsigned short g_abig[NSLOT][NVARS*KBIG]; // [hi|lo|hi] of nv1
__device__ __align__(16) unsigned short g_bbig[NSLOT][NVARS*KBIG]; // [hi|hi|lo] of nv2
__device__ unsigned g_hist[NSLOT][2048];
__device__ unsigned g_cand[NSLOT][CAP];
__device__ unsigned g_state[NSLOT][16];
// state: 0 primary, 1 first_occ, 2 prefix, 3 krem, 4 tu, 7 cutoff, 8 cand_cnt
__device__ float g_scal[2];

__device__ __forceinline__ unsigned fkey(float x){
  unsigned b = __float_as_uint(x);
  return (b & 0x80000000u) ? ~b : (b | 0x80000000u);
}
__device__ __forceinline__ unsigned short f2bf(float v){
  unsigned u = __float_as_uint(v);
  return (unsigned short)((u + 0x7FFFu + ((u >> 16) & 1u)) >> 16);
}
__device__ __forceinline__ void async16(void* lds, const void* g){
  __builtin_amdgcn_global_load_lds(
      (const __attribute__((address_space(1))) unsigned int*)g,
      (__attribute__((address_space(3))) unsigned int*)lds, 16, 0, 0);
}

// ---------------- prep ----------------
__global__ __launch_bounds__(256) void k_prep(const int* __restrict__ tind,
                                              const int* __restrict__ epoch_p){
  int tid = threadIdx.x;
  if (tid < NSLOT){
    int t = tind[tid];
    int fo = tid;
    for (int b = 0; b < tid; b++){ if (tind[b] == t){ fo = b; break; } }
    g_state[tid][0] = (fo == tid) ? 1u : 0u;
    g_state[tid][1] = (unsigned)fo;
    g_state[tid][2] = 0u;
    g_state[tid][3] = K_SEL;
    g_state[tid][4] = 0u;
    g_state[tid][7] = 0x7FFFFFFFu;
    g_state[tid][8] = 0u;
  }
  if (tid == 0){
    double pd = (double)epoch_p[0] / 5.0;
    if (pd > 0.9) pd = 0.9;
    g_scal[0] = (float)(1.0 - pd);
    g_scal[1] = (float)pd;
  }
  unsigned* h = (unsigned*)g_hist;
  for (int i = tid; i < NSLOT*2048; i += 256) h[i] = 0u;
}

// ---------------- GEMM1 (fp32 vector): nv = tanh(E @ W^T + b) -> split bf16 pack
__global__ __launch_bounds__(256) void k_gemm_nv(
    const float* __restrict__ emb1, const float* __restrict__ emb2,
    const float* __restrict__ w1,  const float* __restrict__ b1,
    const float* __restrict__ w2,  const float* __restrict__ b2,
    const int* __restrict__ tind){
  int z = blockIdx.z; int s = z >> 1; int side = z & 1;
  if (!g_state[s][0]) return;
  int t = tind[s];
  const float* E    = (side ? emb2 : emb1) + (size_t)t*NVARS*DG;
  const float* W    = (side ? w2 : w1)     + (size_t)t*DG*DG;
  const float* bias = (side ? b2 : b1)     + (size_t)t*DG;
  unsigned short* dst = side ? g_bbig[s] : g_abig[s];
  int rowBase = blockIdx.y*TS, colBase = blockIdx.x*TS;
  __shared__ float At[KC][TSP];
  __shared__ float Bt[KC][TSP];
  int tid = threadIdx.x;
  int lane = tid & 63, wv = tid >> 6;
  int lx = lane & 7, ly = lane >> 3;
  int rO = (wv >> 1)*64 + ly*8;
  int cO = (wv & 1)*64 + lx*8;
  float acc[8][8] = {};
  for (int k0 = 0; k0 < DG; k0 += KC){
    for (int f = tid; f < TS*KC/4; f += 256){
      int rr = f >> 3, kq = f & 7;
      float4 v = *(const float4*)(E + (size_t)(rowBase+rr)*DG + k0 + kq*4);
      At[kq*4+0][rr]=v.x; At[kq*4+1][rr]=v.y; At[kq*4+2][rr]=v.z; At[kq*4+3][rr]=v.w;
    }
    for (int f = tid; f < TS*KC/4; f += 256){
      int rr = f >> 3, kq = f & 7;
      float4 v = *(const float4*)(W + (size_t)(colBase+rr)*DG + k0 + kq*4);
      Bt[kq*4+0][rr]=v.x; Bt[kq*4+1][rr]=v.y; Bt[kq*4+2][rr]=v.z; Bt[kq*4+3][rr]=v.w;
    }
    __syncthreads();
    #pragma unroll 4
    for (int kk = 0; kk < KC; kk++){
      float a[8], b[8];
      *(float4*)&a[0] = *(const float4*)&At[kk][rO];
      *(float4*)&a[4] = *(const float4*)&At[kk][rO+4];
      *(float4*)&b[0] = *(const float4*)&Bt[kk][cO];
      *(float4*)&b[4] = *(const float4*)&Bt[kk][cO+4];
      #pragma unroll
      for (int i = 0; i < 8; i++)
        #pragma unroll
        for (int j = 0; j < 8; j++) acc[i][j] += a[i]*b[j];
    }
    __syncthreads();
  }
  float bv[8];
  #pragma unroll
  for (int j = 0; j < 8; j++) bv[j] = bias[colBase + cO + j];
  int c0 = colBase + cO;
  for (int i = 0; i < 8; i++){
    int r = rowBase + rO + i;
    ushort8 hi8, lo8;
    #pragma unroll
    for (int j = 0; j < 8; j++){
      float v = tanhf(acc[i][j] + bv[j]);
      unsigned short hb = f2bf(v);
      float hv = __uint_as_float(((unsigned)hb) << 16);
      unsigned short lb = f2bf(v - hv);
      hi8[j] = hb; lo8[j] = lb;
    }
    unsigned short* rp = dst + (size_t)r*KBIG;
    if (side == 0){
      *(ushort8*)(rp + c0)       = hi8;
      *(ushort8*)(rp + 256 + c0) = lo8;
      *(ushort8*)(rp + 512 + c0) = hi8;
    } else {
      *(ushort8*)(rp + c0)       = hi8;
      *(ushort8*)(rp + 256 + c0) = hi8;
      *(ushort8*)(rp + 512 + c0) = lo8;
    }
  }
}

// ---------------- GEMM2 (bf16 MFMA, K=768 split): a = (1-p)*init + p*(nv1@nv2^T)
// diag=-inf, fused pass-1 histogram (2048 bins of fkey>>21)
__global__ __launch_bounds__(256) void k_gemm_s(const float* __restrict__ init,
                                                float* __restrict__ out){
  int s = blockIdx.z;
  if (!g_state[s][0]) return;
  const unsigned short* __restrict__ A = g_abig[s];
  const unsigned short* __restrict__ B = g_bbig[s];
  __shared__ __align__(16) unsigned short As[128*64];
  __shared__ __align__(16) unsigned short Bs[128*64];
  __shared__ unsigned hh[2048];
  int tid = threadIdx.x;
  for (int i = tid; i < 2048; i += 256) hh[i] = 0u;
  int lane = tid & 63, wv = tid >> 6;
  int rowBase = blockIdx.y*128, colBase = blockIdx.x*128;
  int rW = (wv >> 1)*64, cW = (wv & 1)*64;
  int m = lane & 15, q = lane >> 4;
  int rl = lane >> 3, sl = lane & 7;
  floatx4 acc[4][4] = {};
  for (int k0 = 0; k0 < KBIG; k0 += 64){
    #pragma unroll
    for (int t = 0; t < 4; t++){
      int rloc = wv*32 + t*8 + rl;
      int g = sl ^ (rloc & 7);
      async16(&As[(wv*32 + t*8)*64], A + (size_t)(rowBase + rloc)*KBIG + k0 + g*8);
      async16(&Bs[(wv*32 + t*8)*64], B + (size_t)(colBase + rloc)*KBIG + k0 + g*8);
    }
    __syncthreads();
    #pragma unroll
    for (int kk = 0; kk < 2; kk++){
      short8 af[4], bfr[4];
      #pragma unroll
      for (int i = 0; i < 4; i++){
        int rA = rW + i*16 + m;
        af[i]  = *(const short8*)&As[rA*64 + (((kk*4 + q) ^ (rA & 7))*8)];
        int rB = cW + i*16 + m;
        bfr[i] = *(const short8*)&Bs[rB*64 + (((kk*4 + q) ^ (rB & 7))*8)];
      }
      #pragma unroll
      for (int i = 0; i < 4; i++)
        #pragma unroll
        for (int j = 0; j < 4; j++)
          acc[i][j] = __builtin_amdgcn_mfma_f32_16x16x32_bf16(af[i], bfr[j], acc[i][j], 0, 0, 0);
    }
    __syncthreads();
  }
  float am1 = g_scal[0], am2 = g_scal[1];
  float* __restrict__ outs = out + (size_t)s*NN2;
  #pragma unroll
  for (int i = 0; i < 4; i++){
    #pragma unroll
    for (int j = 0; j < 4; j++){
      int col = colBase + cW + j*16 + m;
      #pragma unroll
      for (int r = 0; r < 4; r++){
        int row = rowBase + rW + i*16 + q*4 + r;
        float val = am1*init[(size_t)row*NVARS + col] + am2*acc[i][j][r];
        if (row == col) val = -__builtin_inff();
        outs[(size_t)row*NVARS + col] = val;
        atomicAdd(&hh[fkey(val) >> 21], 1u);
      }
    }
  }
  __syncthreads();
  for (int i = tid; i < 2048; i += 256){
    unsigned c = hh[i];
    if (c) atomicAdd(&g_hist[s][i], c);
  }
}

// ---------------- shared select helpers ----------------
__device__ void desc_select(unsigned* h, unsigned* sc, int nb, unsigned rank,
                            unsigned* od, unsigned* orem, unsigned* ocnt){
  int tid = threadIdx.x;
  int per = nb >> 8;
  unsigned loc[8];
  unsigned own = 0;
  int base = tid*per;
  for (int j = 0; j < per; j++){ loc[j] = h[base+j]; own += loc[j]; }
  sc[tid] = own;
  __syncthreads();
  for (int off = 1; off < 256; off <<= 1){
    unsigned v = (tid + off < 256) ? sc[tid+off] : 0u;
    __syncthreads();
    sc[tid] += v;
    __syncthreads();
  }
  unsigned acc = sc[tid] - own;  // strictly-higher threads
  for (int j = per-1; j >= 0; j--){
    unsigned c = loc[j];
    if (c && rank > acc && rank <= acc + c){ *od = (unsigned)(base+j); *orem = rank - acc; *ocnt = c; }
    acc += c;
  }
  __syncthreads();
}
__device__ void asc_select(unsigned* h, unsigned* sc, int nb, unsigned rank,
                           unsigned* od, unsigned* orem){
  int tid = threadIdx.x;
  int per = nb >> 8;
  unsigned loc[8];
  unsigned own = 0;
  int base = tid*per;
  for (int j = 0; j < per; j++){ loc[j] = h[base+j]; own += loc[j]; }
  sc[tid] = own;
  __syncthreads();
  for (int off = 1; off < 256; off <<= 1){
    unsigned v = (tid >= off) ? sc[tid-off] : 0u;
    __syncthreads();
    sc[tid] += v;
    __syncthreads();
  }
  unsigned below = sc[tid] - own;
  for (int j = 0; j < per; j++){
    unsigned c = loc[j];
    if (c && rank > below && rank <= below + c){ *od = (unsigned)(base+j); *orem = rank - below; }
    below += c;
  }
  __syncthreads();
}

// ---------------- pass-1 bin select ----------------
__global__ __launch_bounds__(256) void k_select1(){
  int s = blockIdx.x;
  if (!g_state[s][0]) return;
  int tid = threadIdx.x;
  __shared__ unsigned h[2048];
  __shared__ unsigned sc[256];
  __shared__ unsigned sd, srem, scnt;
  for (int i = tid; i < 2048; i += 256) h[i] = g_hist[s][i];
  if (tid == 0){ sd = 0; srem = 1; scnt = 1; }
  __syncthreads();
  desc_select(h, sc, 2048, K_SEL, &sd, &srem, &scnt);
  if (tid == 0){ g_state[s][2] = sd << 21; g_state[s][3] = srem; }
}

// ---------------- compact candidate indices in selected bin ----------------
__global__ __launch_bounds__(256) void k_collect(const float* __restrict__ out){
  int s = blockIdx.z;
  if (!g_state[s][0]) return;
  unsigned pb = g_state[s][2] >> 21;
  const float4* p = (const float4*)(out + (size_t)s*NN2);
  int stride = gridDim.x*256;
  for (int i = blockIdx.x*256 + threadIdx.x; i < NN2/4; i += stride){
    float4 v = p[i];
    float xs[4] = {v.x, v.y, v.z, v.w};
    #pragma unroll
    for (int j = 0; j < 4; j++){
      if ((fkey(xs[j]) >> 21) == pb){
        unsigned pos = atomicAdd(&g_state[s][8], 1u);
        if (pos < CAP) g_cand[s][pos] = (unsigned)(i*4 + j);
      }
    }
  }
}

// ---------------- exact threshold + index tie-break among candidates --------
__global__ __launch_bounds__(256) void k_final(const float* __restrict__ out){
  int s = blockIdx.x;
  if (!g_state[s][0]) return;
  int tid = threadIdx.x;
  unsigned mcnt = g_state[s][8]; if (mcnt > CAP) mcnt = CAP;
  unsigned krem = g_state[s][3];
  unsigned prefix = g_state[s][2];
  const float* outs = out + (size_t)s*NN2;
  __shared__ unsigned h[2048];
  __shared__ unsigned sc[256];
  __shared__ unsigned sd, srem, scnt;
  // phase 1: fkey bits 20..10
  for (int i = tid; i < 2048; i += 256) h[i] = 0u;
  if (tid == 0){ sd = 0; srem = 1; scnt = 1; }
  __syncthreads();
  for (unsigned i = tid; i < mcnt; i += 256){
    unsigned u = fkey(outs[g_cand[s][i]]);
    atomicAdd(&h[(u >> 10) & 0x7FFu], 1u);
  }
  __syncthreads();
  desc_select(h, sc, 2048, krem, &sd, &srem, &scnt);
  unsigned d1 = sd, krem2 = srem;
  __syncthreads();
  // phase 2: fkey bits 9..0
  for (int i = tid; i < 2048; i += 256) h[i] = 0u;
  __syncthreads();
  for (unsigned i = tid; i < mcnt; i += 256){
    unsigned u = fkey(outs[g_cand[s][i]]);
    if (((u >> 10) & 0x7FFu) == d1) atomicAdd(&h[u & 0x3FFu], 1u);
  }
  __syncthreads();
  desc_select(h, sc, 1024, krem2, &sd, &srem, &scnt);
  unsigned d0 = sd, nek = srem, cnteq = scnt;
  __syncthreads();
  unsigned tu = prefix | (d1 << 10) | d0;
  unsigned cutoff = 0x7FFFFFFFu;
  if (nek < cnteq){
    // phase 3: nek-th smallest index, high 11 bits
    for (int i = tid; i < 2048; i += 256) h[i] = 0u;
    __syncthreads();
    for (unsigned i = tid; i < mcnt; i += 256){
      unsigned idx = g_cand[s][i];
      if (fkey(outs[idx]) == tu) atomicAdd(&h[idx >> 11], 1u);
    }
    __syncthreads();
    asc_select(h, sc, 2048, nek, &sd, &srem);
    unsigned dh = sd, j2 = srem;
    __syncthreads();
    // phase 4: low 11 bits
    for (int i = tid; i < 2048; i += 256) h[i] = 0u;
    __syncthreads();
    for (unsigned i = tid; i < mcnt; i += 256){
      unsigned idx = g_cand[s][i];
      if (fkey(outs[idx]) == tu && (idx >> 11) == dh) atomicAdd(&h[idx & 0x7FFu], 1u);
    }
    __syncthreads();
    asc_select(h, sc, 2048, j2, &sd, &srem);
    cutoff = (dh << 11) | sd;
    __syncthreads();
  }
  if (tid == 0){ g_state[s][4] = tu; g_state[s][7] = cutoff; }
}

// ---------------- mask + tanh/relu + eye + normalize + multicast to dups ----
__global__ __launch_bounds__(256) void k_masknorm(float* __restrict__ out){
  int s = blockIdx.y;
  if (!g_state[s][0]) return;
  int r = blockIdx.x;
  int tid = threadIdx.x;
  unsigned tu = g_state[s][4];
  unsigned cutoff = g_state[s][7];
  const float4* rowp = (const float4*)(out + (size_t)s*NN2 + (size_t)r*NVARS);
  unsigned baseIdx = (unsigned)(r*NVARS);
  float4 res[2];
  double lsum = 0.0;
  #pragma unroll
  for (int t = 0; t < 2; t++){
    int c4 = tid + t*256;
    float4 a4 = rowp[c4];
    float av[4] = {a4.x, a4.y, a4.z, a4.w};
    float rv[4];
    #pragma unroll
    for (int j = 0; j < 4; j++){
      int c = c4*4 + j;
      float vv;
      if (c == r) vv = 1.0f;
      else {
        unsigned u = fkey(av[j]);
        bool keep = (u > tu) || (u == tu && (baseIdx + (unsigned)c) <= cutoff);
        vv = keep ? fmaxf(tanhf(av[j]), 0.0f) : 0.0f;
      }
      rv[j] = vv;
      lsum += (double)vv;
    }
    res[t].x = rv[0]; res[t].y = rv[1]; res[t].z = rv[2]; res[t].w = rv[3];
  }
  __shared__ double red[256];
  red[tid] = lsum;
  __syncthreads();
  for (int off = 128; off > 0; off >>= 1){
    if (tid < off) red[tid] += red[tid+off];
    __syncthreads();
  }
  float inv = 1.0f / (float)red[0];
  #pragma unroll
  for (int t = 0; t < 2; t++){
    res[t].x *= inv; res[t].y *= inv; res[t].z *= inv; res[t].w *= inv;
  }
  for (int s2 = 0; s2 < NSLOT; s2++){
    if (g_state[s2][1] == (unsigned)s){
      float4* dst = (float4*)(out + (size_t)s2*NN2 + (size_t)r*NVARS);
      dst[tid]       = res[0];
      dst[tid + 256] = res[1];
    }
  }
}

// ---------------- host launcher ----------------
extern "C" void kernel_launch(void* const* d_in, const int* in_sizes, int n_in,
                              void* d_out, int out_size, void* d_ws, size_t ws_size,
                              hipStream_t stream){
  (void)in_sizes; (void)n_in; (void)d_ws; (void)ws_size; (void)out_size;
  const float* init = (const float*)d_in[0];
  const float* emb1 = (const float*)d_in[1];
  const float* emb2 = (const float*)d_in[2];
  const float* w1   = (const float*)d_in[3];
  const float* b1   = (const float*)d_in[4];
  const float* w2   = (const float*)d_in[5];
  const float* b2   = (const float*)d_in[6];
  const int* tind   = (const int*)d_in[7];
  const int* epoch  = (const int*)d_in[8];
  float* out = (float*)d_out;

  k_prep<<<1, 256, 0, stream>>>(tind, epoch);
  k_gemm_nv<<<dim3(2, 16, 16), 256, 0, stream>>>(emb1, emb2, w1, b1, w2, b2, tind);
  k_gemm_s<<<dim3(16, 16, 8), 256, 0, stream>>>(init, out);
  k_select1<<<8, 256, 0, stream>>>();
  k_collect<<<dim3(256, 1, 8), 256, 0, stream>>>(out);
  k_final<<<8, 256, 0, stream>>>(out);
  k_masknorm<<<dim3(2048, 8), 256, 0, stream>>>(out);
}

// Round 3
// 469.860 us; speedup vs baseline: 1.2467x; 1.0642x over previous
//
#include <hip/hip_runtime.h>
#include <cstdint>
#include <cstddef>

#define NVARS 2048
#define DG    256
#define NSLOT 8
#define NN2   (NVARS*NVARS)
#define K_SEL 2097152u
#define CAP   (1u<<18)
#define TS 128
#define KC 32
#define TSP (TS+4)
#define KBIG 768

typedef __attribute__((ext_vector_type(8))) short short8;
typedef __attribute__((ext_vector_type(8))) unsigned short ushort8;
typedef __attribute__((ext_vector_type(4))) float floatx4;

// ---------------- static device scratch ----------------
__device__ __align__(16) unsigned short g_abig[NSLOT][NVARS*KBIG]; // [hi|lo|hi] of nv1
__device__ __align__(16) unsigned short g_bbig[NSLOT][NVARS*KBIG]; // [hi|hi|lo] of nv2
__device__ unsigned g_hist[NSLOT][2048];
__device__ unsigned g_cand[NSLOT][CAP];
__device__ unsigned g_state[NSLOT][16];
// state: 0 primary, 1 first_occ, 2 prefix, 3 krem, 4 tu, 7 cutoff, 8 cand_cnt
__device__ float g_scal[2];

__device__ __forceinline__ unsigned fkey(float x){
  unsigned b = __float_as_uint(x);
  return (b & 0x80000000u) ? ~b : (b | 0x80000000u);
}
__device__ __forceinline__ unsigned short f2bf(float v){
  unsigned u = __float_as_uint(v);
  return (unsigned short)((u + 0x7FFFu + ((u >> 16) & 1u)) >> 16);
}
__device__ __forceinline__ void async16(void* lds, const void* g){
  __builtin_amdgcn_global_load_lds(
      (const __attribute__((address_space(1))) unsigned int*)g,
      (__attribute__((address_space(3))) unsigned int*)lds, 16, 0, 0);
}

// ---------------- prep ----------------
__global__ __launch_bounds__(256) void k_prep(const int* __restrict__ tind,
                                              const int* __restrict__ epoch_p){
  int tid = threadIdx.x;
  if (tid < NSLOT){
    int t = tind[tid];
    int fo = tid;
    for (int b = 0; b < tid; b++){ if (tind[b] == t){ fo = b; break; } }
    g_state[tid][0] = (fo == tid) ? 1u : 0u;
    g_state[tid][1] = (unsigned)fo;
    g_state[tid][2] = 0u;
    g_state[tid][3] = K_SEL;
    g_state[tid][4] = 0u;
    g_state[tid][7] = 0x7FFFFFFFu;
    g_state[tid][8] = 0u;
  }
  if (tid == 0){
    double pd = (double)epoch_p[0] / 5.0;
    if (pd > 0.9) pd = 0.9;
    g_scal[0] = (float)(1.0 - pd);
    g_scal[1] = (float)pd;
  }
  unsigned* h = (unsigned*)g_hist;
  for (int i = tid; i < NSLOT*2048; i += 256) h[i] = 0u;
}

// ---------------- GEMM1 (fp32 vector): nv = tanh(E @ W^T + b) -> split bf16 pack
// __launch_bounds__(256,2): 256-VGPR cap so acc[8][8] stays in registers (no spill)
__global__ __launch_bounds__(256, 2) void k_gemm_nv(
    const float* __restrict__ emb1, const float* __restrict__ emb2,
    const float* __restrict__ w1,  const float* __restrict__ b1,
    const float* __restrict__ w2,  const float* __restrict__ b2,
    const int* __restrict__ tind){
  int z = blockIdx.z; int s = z >> 1; int side = z & 1;
  if (!g_state[s][0]) return;
  int t = tind[s];
  const float* E    = (side ? emb2 : emb1) + (size_t)t*NVARS*DG;
  const float* W    = (side ? w2 : w1)     + (size_t)t*DG*DG;
  const float* bias = (side ? b2 : b1)     + (size_t)t*DG;
  unsigned short* dst = side ? g_bbig[s] : g_abig[s];
  int rowBase = blockIdx.y*TS, colBase = blockIdx.x*TS;
  __shared__ float At[KC][TSP];
  __shared__ float Bt[KC][TSP];
  int tid = threadIdx.x;
  int lane = tid & 63, wv = tid >> 6;
  int lx = lane & 7, ly = lane >> 3;
  int rO = (wv >> 1)*64 + ly*8;
  int cO = (wv & 1)*64 + lx*8;
  float acc[8][8] = {};
  for (int k0 = 0; k0 < DG; k0 += KC){
    for (int f = tid; f < TS*KC/4; f += 256){
      int rr = f >> 3, kq = f & 7;
      float4 v = *(const float4*)(E + (size_t)(rowBase+rr)*DG + k0 + kq*4);
      At[kq*4+0][rr]=v.x; At[kq*4+1][rr]=v.y; At[kq*4+2][rr]=v.z; At[kq*4+3][rr]=v.w;
    }
    for (int f = tid; f < TS*KC/4; f += 256){
      int rr = f >> 3, kq = f & 7;
      float4 v = *(const float4*)(W + (size_t)(colBase+rr)*DG + k0 + kq*4);
      Bt[kq*4+0][rr]=v.x; Bt[kq*4+1][rr]=v.y; Bt[kq*4+2][rr]=v.z; Bt[kq*4+3][rr]=v.w;
    }
    __syncthreads();
    #pragma unroll 4
    for (int kk = 0; kk < KC; kk++){
      float a[8], b[8];
      *(float4*)&a[0] = *(const float4*)&At[kk][rO];
      *(float4*)&a[4] = *(const float4*)&At[kk][rO+4];
      *(float4*)&b[0] = *(const float4*)&Bt[kk][cO];
      *(float4*)&b[4] = *(const float4*)&Bt[kk][cO+4];
      #pragma unroll
      for (int i = 0; i < 8; i++)
        #pragma unroll
        for (int j = 0; j < 8; j++) acc[i][j] += a[i]*b[j];
    }
    __syncthreads();
  }
  float bv[8];
  #pragma unroll
  for (int j = 0; j < 8; j++) bv[j] = bias[colBase + cO + j];
  int c0 = colBase + cO;
  for (int i = 0; i < 8; i++){
    int r = rowBase + rO + i;
    ushort8 hi8, lo8;
    #pragma unroll
    for (int j = 0; j < 8; j++){
      float v = tanhf(acc[i][j] + bv[j]);
      unsigned short hb = f2bf(v);
      float hv = __uint_as_float(((unsigned)hb) << 16);
      unsigned short lb = f2bf(v - hv);
      hi8[j] = hb; lo8[j] = lb;
    }
    unsigned short* rp = dst + (size_t)r*KBIG;
    if (side == 0){
      *(ushort8*)(rp + c0)       = hi8;
      *(ushort8*)(rp + 256 + c0) = lo8;
      *(ushort8*)(rp + 512 + c0) = hi8;
    } else {
      *(ushort8*)(rp + c0)       = hi8;
      *(ushort8*)(rp + 256 + c0) = hi8;
      *(ushort8*)(rp + 512 + c0) = lo8;
    }
  }
}

// ---------------- GEMM2 (bf16 MFMA, K=768 split): a = (1-p)*init + p*(nv1@nv2^T)
// diag=-inf; NO fused histogram (LDS-atomic contention) — pure stores.
__global__ __launch_bounds__(256, 2) void k_gemm_s(const float* __restrict__ init,
                                                   float* __restrict__ out){
  int s = blockIdx.z;
  if (!g_state[s][0]) return;
  const unsigned short* __restrict__ A = g_abig[s];
  const unsigned short* __restrict__ B = g_bbig[s];
  __shared__ __align__(16) unsigned short As[128*64];
  __shared__ __align__(16) unsigned short Bs[128*64];
  int tid = threadIdx.x;
  int lane = tid & 63, wv = tid >> 6;
  int rowBase = blockIdx.y*128, colBase = blockIdx.x*128;
  int rW = (wv >> 1)*64, cW = (wv & 1)*64;
  int m = lane & 15, q = lane >> 4;
  int rl = lane >> 3, sl = lane & 7;
  floatx4 acc[4][4] = {};
  for (int k0 = 0; k0 < KBIG; k0 += 64){
    #pragma unroll
    for (int t = 0; t < 4; t++){
      int rloc = wv*32 + t*8 + rl;
      int g = sl ^ (rloc & 7);
      async16(&As[(wv*32 + t*8)*64], A + (size_t)(rowBase + rloc)*KBIG + k0 + g*8);
      async16(&Bs[(wv*32 + t*8)*64], B + (size_t)(colBase + rloc)*KBIG + k0 + g*8);
    }
    __syncthreads();
    #pragma unroll
    for (int kk = 0; kk < 2; kk++){
      short8 af[4], bfr[4];
      #pragma unroll
      for (int i = 0; i < 4; i++){
        int rA = rW + i*16 + m;
        af[i]  = *(const short8*)&As[rA*64 + (((kk*4 + q) ^ (rA & 7))*8)];
        int rB = cW + i*16 + m;
        bfr[i] = *(const short8*)&Bs[rB*64 + (((kk*4 + q) ^ (rB & 7))*8)];
      }
      #pragma unroll
      for (int i = 0; i < 4; i++)
        #pragma unroll
        for (int j = 0; j < 4; j++)
          acc[i][j] = __builtin_amdgcn_mfma_f32_16x16x32_bf16(af[i], bfr[j], acc[i][j], 0, 0, 0);
    }
    __syncthreads();
  }
  float am1 = g_scal[0], am2 = g_scal[1];
  float* __restrict__ outs = out + (size_t)s*NN2;
  #pragma unroll
  for (int i = 0; i < 4; i++){
    #pragma unroll
    for (int j = 0; j < 4; j++){
      int col = colBase + cW + j*16 + m;
      #pragma unroll
      for (int r = 0; r < 4; r++){
        int row = rowBase + rW + i*16 + q*4 + r;
        float val = am1*init[(size_t)row*NVARS + col] + am2*acc[i][j][r];
        if (row == col) val = -__builtin_inff();
        outs[(size_t)row*NVARS + col] = val;
      }
    }
  }
}

// ---------------- pass-1 histogram (standalone streaming pass) --------------
__global__ __launch_bounds__(256) void k_hist1(const float* __restrict__ out){
  int s = blockIdx.z;
  if (!g_state[s][0]) return;
  __shared__ unsigned h[2048];
  int tid = threadIdx.x;
  for (int i = tid; i < 2048; i += 256) h[i] = 0u;
  __syncthreads();
  const float4* p = (const float4*)(out + (size_t)s*NN2);
  int stride = gridDim.x*256;
  for (int i = blockIdx.x*256 + tid; i < NN2/4; i += stride){
    float4 v = p[i];
    float xs[4] = {v.x, v.y, v.z, v.w};
    #pragma unroll
    for (int j = 0; j < 4; j++) atomicAdd(&h[fkey(xs[j]) >> 21], 1u);
  }
  __syncthreads();
  for (int i = tid; i < 2048; i += 256){
    unsigned c = h[i];
    if (c) atomicAdd(&g_hist[s][i], c);
  }
}

// ---------------- shared select helpers ----------------
__device__ void desc_select(unsigned* h, unsigned* sc, int nb, unsigned rank,
                            unsigned* od, unsigned* orem, unsigned* ocnt){
  int tid = threadIdx.x;
  int per = nb >> 8;
  unsigned loc[8];
  unsigned own = 0;
  int base = tid*per;
  for (int j = 0; j < per; j++){ loc[j] = h[base+j]; own += loc[j]; }
  sc[tid] = own;
  __syncthreads();
  for (int off = 1; off < 256; off <<= 1){
    unsigned v = (tid + off < 256) ? sc[tid+off] : 0u;
    __syncthreads();
    sc[tid] += v;
    __syncthreads();
  }
  unsigned acc = sc[tid] - own;  // strictly-higher threads
  for (int j = per-1; j >= 0; j--){
    unsigned c = loc[j];
    if (c && rank > acc && rank <= acc + c){ *od = (unsigned)(base+j); *orem = rank - acc; *ocnt = c; }
    acc += c;
  }
  __syncthreads();
}
__device__ void asc_select(unsigned* h, unsigned* sc, int nb, unsigned rank,
                           unsigned* od, unsigned* orem){
  int tid = threadIdx.x;
  int per = nb >> 8;
  unsigned loc[8];
  unsigned own = 0;
  int base = tid*per;
  for (int j = 0; j < per; j++){ loc[j] = h[base+j]; own += loc[j]; }
  sc[tid] = own;
  __syncthreads();
  for (int off = 1; off < 256; off <<= 1){
    unsigned v = (tid >= off) ? sc[tid-off] : 0u;
    __syncthreads();
    sc[tid] += v;
    __syncthreads();
  }
  unsigned below = sc[tid] - own;
  for (int j = 0; j < per; j++){
    unsigned c = loc[j];
    if (c && rank > below && rank <= below + c){ *od = (unsigned)(base+j); *orem = rank - below; }
    below += c;
  }
  __syncthreads();
}

// ---------------- pass-1 bin select ----------------
__global__ __launch_bounds__(256) void k_select1(){
  int s = blockIdx.x;
  if (!g_state[s][0]) return;
  int tid = threadIdx.x;
  __shared__ unsigned h[2048];
  __shared__ unsigned sc[256];
  __shared__ unsigned sd, srem, scnt;
  for (int i = tid; i < 2048; i += 256) h[i] = g_hist[s][i];
  if (tid == 0){ sd = 0; srem = 1; scnt = 1; }
  __syncthreads();
  desc_select(h, sc, 2048, K_SEL, &sd, &srem, &scnt);
  if (tid == 0){ g_state[s][2] = sd << 21; g_state[s][3] = srem; }
}

// ---------------- compact candidate indices in selected bin ----------------
__global__ __launch_bounds__(256) void k_collect(const float* __restrict__ out){
  int s = blockIdx.z;
  if (!g_state[s][0]) return;
  unsigned pb = g_state[s][2] >> 21;
  const float4* p = (const float4*)(out + (size_t)s*NN2);
  int stride = gridDim.x*256;
  for (int i = blockIdx.x*256 + threadIdx.x; i < NN2/4; i += stride){
    float4 v = p[i];
    float xs[4] = {v.x, v.y, v.z, v.w};
    #pragma unroll
    for (int j = 0; j < 4; j++){
      if ((fkey(xs[j]) >> 21) == pb){
        unsigned pos = atomicAdd(&g_state[s][8], 1u);
        if (pos < CAP) g_cand[s][pos] = (unsigned)(i*4 + j);
      }
    }
  }
}

// ---------------- exact threshold + index tie-break among candidates --------
__global__ __launch_bounds__(256) void k_final(const float* __restrict__ out){
  int s = blockIdx.x;
  if (!g_state[s][0]) return;
  int tid = threadIdx.x;
  unsigned mcnt = g_state[s][8]; if (mcnt > CAP) mcnt = CAP;
  unsigned krem = g_state[s][3];
  unsigned prefix = g_state[s][2];
  const float* outs = out + (size_t)s*NN2;
  __shared__ unsigned h[2048];
  __shared__ unsigned sc[256];
  __shared__ unsigned sd, srem, scnt;
  // phase 1: fkey bits 20..10
  for (int i = tid; i < 2048; i += 256) h[i] = 0u;
  if (tid == 0){ sd = 0; srem = 1; scnt = 1; }
  __syncthreads();
  for (unsigned i = tid; i < mcnt; i += 256){
    unsigned u = fkey(outs[g_cand[s][i]]);
    atomicAdd(&h[(u >> 10) & 0x7FFu], 1u);
  }
  __syncthreads();
  desc_select(h, sc, 2048, krem, &sd, &srem, &scnt);
  unsigned d1 = sd, krem2 = srem;
  __syncthreads();
  // phase 2: fkey bits 9..0
  for (int i = tid; i < 2048; i += 256) h[i] = 0u;
  __syncthreads();
  for (unsigned i = tid; i < mcnt; i += 256){
    unsigned u = fkey(outs[g_cand[s][i]]);
    if (((u >> 10) & 0x7FFu) == d1) atomicAdd(&h[u & 0x3FFu], 1u);
  }
  __syncthreads();
  desc_select(h, sc, 1024, krem2, &sd, &srem, &scnt);
  unsigned d0 = sd, nek = srem, cnteq = scnt;
  __syncthreads();
  unsigned tu = prefix | (d1 << 10) | d0;
  unsigned cutoff = 0x7FFFFFFFu;
  if (nek < cnteq){
    // phase 3: nek-th smallest index, high 11 bits
    for (int i = tid; i < 2048; i += 256) h[i] = 0u;
    __syncthreads();
    for (unsigned i = tid; i < mcnt; i += 256){
      unsigned idx = g_cand[s][i];
      if (fkey(outs[idx]) == tu) atomicAdd(&h[idx >> 11], 1u);
    }
    __syncthreads();
    asc_select(h, sc, 2048, nek, &sd, &srem);
    unsigned dh = sd, j2 = srem;
    __syncthreads();
    // phase 4: low 11 bits
    for (int i = tid; i < 2048; i += 256) h[i] = 0u;
    __syncthreads();
    for (unsigned i = tid; i < mcnt; i += 256){
      unsigned idx = g_cand[s][i];
      if (fkey(outs[idx]) == tu && (idx >> 11) == dh) atomicAdd(&h[idx & 0x7FFu], 1u);
    }
    __syncthreads();
    asc_select(h, sc, 2048, j2, &sd, &srem);
    cutoff = (dh << 11) | sd;
    __syncthreads();
  }
  if (tid == 0){ g_state[s][4] = tu; g_state[s][7] = cutoff; }
}

// ---------------- mask + tanh/relu + eye + normalize + multicast to dups ----
__global__ __launch_bounds__(256) void k_masknorm(float* __restrict__ out){
  int s = blockIdx.y;
  if (!g_state[s][0]) return;
  int r = blockIdx.x;
  int tid = threadIdx.x;
  unsigned tu = g_state[s][4];
  unsigned cutoff = g_state[s][7];
  const float4* rowp = (const float4*)(out + (size_t)s*NN2 + (size_t)r*NVARS);
  unsigned baseIdx = (unsigned)(r*NVARS);
  float4 res[2];
  double lsum = 0.0;
  #pragma unroll
  for (int t = 0; t < 2; t++){
    int c4 = tid + t*256;
    float4 a4 = rowp[c4];
    float av[4] = {a4.x, a4.y, a4.z, a4.w};
    float rv[4];
    #pragma unroll
    for (int j = 0; j < 4; j++){
      int c = c4*4 + j;
      float vv;
      if (c == r) vv = 1.0f;
      else {
        unsigned u = fkey(av[j]);
        bool keep = (u > tu) || (u == tu && (baseIdx + (unsigned)c) <= cutoff);
        vv = keep ? fmaxf(tanhf(av[j]), 0.0f) : 0.0f;
      }
      rv[j] = vv;
      lsum += (double)vv;
    }
    res[t].x = rv[0]; res[t].y = rv[1]; res[t].z = rv[2]; res[t].w = rv[3];
  }
  __shared__ double red[256];
  red[tid] = lsum;
  __syncthreads();
  for (int off = 128; off > 0; off >>= 1){
    if (tid < off) red[tid] += red[tid+off];
    __syncthreads();
  }
  float inv = 1.0f / (float)red[0];
  #pragma unroll
  for (int t = 0; t < 2; t++){
    res[t].x *= inv; res[t].y *= inv; res[t].z *= inv; res[t].w *= inv;
  }
  for (int s2 = 0; s2 < NSLOT; s2++){
    if (g_state[s2][1] == (unsigned)s){
      float4* dst = (float4*)(out + (size_t)s2*NN2 + (size_t)r*NVARS);
      dst[tid]       = res[0];
      dst[tid + 256] = res[1];
    }
  }
}

// ---------------- host launcher ----------------
extern "C" void kernel_launch(void* const* d_in, const int* in_sizes, int n_in,
                              void* d_out, int out_size, void* d_ws, size_t ws_size,
                              hipStream_t stream){
  (void)in_sizes; (void)n_in; (void)d_ws; (void)ws_size; (void)out_size;
  const float* init = (const float*)d_in[0];
  const float* emb1 = (const float*)d_in[1];
  const float* emb2 = (const float*)d_in[2];
  const float* w1   = (const float*)d_in[3];
  const float* b1   = (const float*)d_in[4];
  const float* w2   = (const float*)d_in[5];
  const float* b2   = (const float*)d_in[6];
  const int* tind   = (const int*)d_in[7];
  const int* epoch  = (const int*)d_in[8];
  float* out = (float*)d_out;

  k_prep<<<1, 256, 0, stream>>>(tind, epoch);
  k_gemm_nv<<<dim3(2, 16, 16), 256, 0, stream>>>(emb1, emb2, w1, b1, w2, b2, tind);
  k_gemm_s<<<dim3(16, 16, 8), 256, 0, stream>>>(init, out);
  k_hist1<<<dim3(256, 1, 8), 256, 0, stream>>>(out);
  k_select1<<<8, 256, 0, stream>>>();
  k_collect<<<dim3(256, 1, 8), 256, 0, stream>>>(out);
  k_final<<<8, 256, 0, stream>>>(out);
  k_masknorm<<<dim3(2048, 8), 256, 0, stream>>>(out);
}

// Round 4
// 364.795 us; speedup vs baseline: 1.6058x; 1.2880x over previous
//
#include <hip/hip_runtime.h>
#include <cstdint>
#include <cstddef>

#define NVARS 2048
#define DG    256
#define NSLOT 8
#define NN2   (NVARS*NVARS)
#define K_SEL 2097152u
#define CAP   (1u<<18)
#define KS    512   // packed row stride: [hi(256) | lo(256)]

typedef __attribute__((ext_vector_type(8))) short short8;
typedef __attribute__((ext_vector_type(8))) unsigned short ushort8;
typedef __attribute__((ext_vector_type(4))) float floatx4;

// ---------------- static device scratch ----------------
__device__ __align__(16) unsigned short g_ebig[NSLOT][2][NVARS*KS]; // split E (emb1/emb2)
__device__ __align__(16) unsigned short g_wbig[NSLOT][2][DG*KS];    // split W (w1/w2)
__device__ __align__(16) unsigned short g_abig[NSLOT][NVARS*KS];    // split nv1
__device__ __align__(16) unsigned short g_bbig[NSLOT][NVARS*KS];    // split nv2
__device__ unsigned g_hist[NSLOT][2048];
__device__ unsigned g_cand[NSLOT][CAP];
__device__ unsigned g_state[NSLOT][16];
// state: 0 primary, 1 first_occ, 2 prefix, 3 krem, 4 tu, 7 cutoff, 8 cand_cnt
__device__ float g_scal[2];

__device__ __forceinline__ unsigned fkey(float x){
  unsigned b = __float_as_uint(x);
  return (b & 0x80000000u) ? ~b : (b | 0x80000000u);
}
__device__ __forceinline__ unsigned short f2bf(float v){
  unsigned u = __float_as_uint(v);
  return (unsigned short)((u + 0x7FFFu + ((u >> 16) & 1u)) >> 16);
}
__device__ __forceinline__ void async16(void* lds, const void* g){
  __builtin_amdgcn_global_load_lds(
      (const __attribute__((address_space(1))) unsigned int*)g,
      (__attribute__((address_space(3))) unsigned int*)lds, 16, 0, 0);
}

// ---------------- prep ----------------
__global__ __launch_bounds__(256) void k_prep(const int* __restrict__ tind,
                                              const int* __restrict__ epoch_p){
  int tid = threadIdx.x;
  if (tid < NSLOT){
    int t = tind[tid];
    int fo = tid;
    for (int b = 0; b < tid; b++){ if (tind[b] == t){ fo = b; break; } }
    g_state[tid][0] = (fo == tid) ? 1u : 0u;
    g_state[tid][1] = (unsigned)fo;
    g_state[tid][2] = 0u;
    g_state[tid][3] = K_SEL;
    g_state[tid][4] = 0u;
    g_state[tid][7] = 0x7FFFFFFFu;
    g_state[tid][8] = 0u;
  }
  if (tid == 0){
    double pd = (double)epoch_p[0] / 5.0;
    if (pd > 0.9) pd = 0.9;
    g_scal[0] = (float)(1.0 - pd);
    g_scal[1] = (float)pd;
  }
  unsigned* h = (unsigned*)g_hist;
  for (int i = tid; i < NSLOT*2048; i += 256) h[i] = 0u;
}

// ---------------- split E and W into [hi|lo] bf16 (streaming, BW-bound) ----
__global__ __launch_bounds__(256) void k_split(
    const float* __restrict__ emb1, const float* __restrict__ emb2,
    const float* __restrict__ w1,  const float* __restrict__ w2,
    const int* __restrict__ tind){
  int z = blockIdx.z; int s = z >> 1; int side = z & 1;
  if (!g_state[s][0]) return;
  int t = tind[s];
  int flat = blockIdx.x*256 + threadIdx.x;   // 0 .. 73727
  const float* src;
  unsigned short* dst;
  if (flat < 65536){           // E: 2048 rows x 32 granules of 8
    int row = flat >> 5, g8 = flat & 31;
    src = (side ? emb2 : emb1) + (size_t)t*NVARS*DG + (size_t)row*DG + g8*8;
    dst = g_ebig[s][side] + (size_t)row*KS + g8*8;
  } else {                     // W: 256 rows x 32 granules
    int f2 = flat - 65536;
    int row = f2 >> 5, g8 = f2 & 31;
    src = (side ? w2 : w1) + (size_t)t*DG*DG + (size_t)row*DG + g8*8;
    dst = g_wbig[s][side] + (size_t)row*KS + g8*8;
  }
  float4 v0 = *(const float4*)src;
  float4 v1 = *(const float4*)(src + 4);
  float a[8] = {v0.x,v0.y,v0.z,v0.w,v1.x,v1.y,v1.z,v1.w};
  ushort8 hi8, lo8;
  #pragma unroll
  for (int j = 0; j < 8; j++){
    unsigned short hb = f2bf(a[j]);
    float hv = __uint_as_float(((unsigned)hb) << 16);
    hi8[j] = hb;
    lo8[j] = f2bf(a[j] - hv);
  }
  *(ushort8*)dst         = hi8;
  *(ushort8*)(dst + 256) = lo8;
}

// ---------------- GEMM1 (bf16 MFMA, 3-phase split-K): nv = tanh(E@W^T + b) --
// epilogue: LDS bounce -> tanh -> hi/lo split-pack into g_abig/g_bbig
__global__ __launch_bounds__(256, 2) void k_gemm_nv(
    const float* __restrict__ b1, const float* __restrict__ b2,
    const int* __restrict__ tind){
  int z = blockIdx.z; int s = z >> 1; int side = z & 1;
  if (!g_state[s][0]) return;
  int t = tind[s];
  const unsigned short* __restrict__ A = g_ebig[s][side];
  const unsigned short* __restrict__ B = g_wbig[s][side];
  const float* __restrict__ bias = (side ? b2 : b1) + (size_t)t*DG;
  unsigned short* __restrict__ dst = side ? g_bbig[s] : g_abig[s];
  __shared__ __align__(16) unsigned short As[128*64];
  __shared__ __align__(16) unsigned short Bs[128*64];
  __shared__ __align__(16) float Cs[128][68];
  int tid = threadIdx.x;
  int lane = tid & 63, wv = tid >> 6;
  int rowBase = blockIdx.y*128, colBase = blockIdx.x*128;
  int rW = (wv >> 1)*64, cW = (wv & 1)*64;
  int m = lane & 15, q = lane >> 4;
  int rl = lane >> 3, sl = lane & 7;
  floatx4 acc[4][4] = {};
  for (int p = 0; p < 3; p++){
    int aoff = (p == 1) ? 256 : 0;
    int boff = (p == 2) ? 256 : 0;
    for (int k0 = 0; k0 < 256; k0 += 64){
      #pragma unroll
      for (int t4 = 0; t4 < 4; t4++){
        int rloc = wv*32 + t4*8 + rl;
        int g = sl ^ (rloc & 7);
        async16(&As[(wv*32 + t4*8)*64], A + (size_t)(rowBase + rloc)*KS + aoff + k0 + g*8);
        async16(&Bs[(wv*32 + t4*8)*64], B + (size_t)(colBase + rloc)*KS + boff + k0 + g*8);
      }
      __syncthreads();
      #pragma unroll
      for (int kk = 0; kk < 2; kk++){
        short8 af[4], bfr[4];
        #pragma unroll
        for (int i = 0; i < 4; i++){
          int rA = rW + i*16 + m;
          af[i]  = *(const short8*)&As[rA*64 + (((kk*4 + q) ^ (rA & 7))*8)];
          int rB = cW + i*16 + m;
          bfr[i] = *(const short8*)&Bs[rB*64 + (((kk*4 + q) ^ (rB & 7))*8)];
        }
        #pragma unroll
        for (int i = 0; i < 4; i++)
          #pragma unroll
          for (int j = 0; j < 4; j++)
            acc[i][j] = __builtin_amdgcn_mfma_f32_16x16x32_bf16(af[i], bfr[j], acc[i][j], 0, 0, 0);
      }
      __syncthreads();
    }
  }
  // epilogue: two 64-col halves through LDS
  for (int h = 0; h < 2; h++){
    if ((wv & 1) == h){
      #pragma unroll
      for (int i = 0; i < 4; i++)
        #pragma unroll
        for (int j = 0; j < 4; j++)
          #pragma unroll
          for (int r = 0; r < 4; r++)
            Cs[rW + i*16 + q*4 + r][j*16 + m] = acc[i][j][r];
    }
    __syncthreads();
    #pragma unroll
    for (int it = 0; it < 4; it++){
      int row = it*32 + (tid >> 3);
      int c8  = (tid & 7)*8;
      float4 va = *(const float4*)&Cs[row][c8];
      float4 vb = *(const float4*)&Cs[row][c8 + 4];
      float v[8] = {va.x,va.y,va.z,va.w,vb.x,vb.y,vb.z,vb.w};
      int colb = colBase + h*64 + c8;
      ushort8 hi8, lo8;
      #pragma unroll
      for (int j = 0; j < 8; j++){
        float e = tanhf(v[j] + bias[colb + j]);
        unsigned short hb = f2bf(e);
        float hv = __uint_as_float(((unsigned)hb) << 16);
        hi8[j] = hb;
        lo8[j] = f2bf(e - hv);
      }
      unsigned short* rp = dst + (size_t)(rowBase + row)*KS;
      *(ushort8*)(rp + colb)       = hi8;
      *(ushort8*)(rp + 256 + colb) = lo8;
    }
    __syncthreads();
  }
}

// ---------------- GEMM2 (bf16 MFMA, 3-phase split-K): a = (1-p)*init + p*(nv1@nv2^T)
__global__ __launch_bounds__(256, 2) void k_gemm_s(const float* __restrict__ init,
                                                   float* __restrict__ out){
  int s = blockIdx.z;
  if (!g_state[s][0]) return;
  const unsigned short* __restrict__ A = g_abig[s];
  const unsigned short* __restrict__ B = g_bbig[s];
  __shared__ __align__(16) unsigned short As[128*64];
  __shared__ __align__(16) unsigned short Bs[128*64];
  int tid = threadIdx.x;
  int lane = tid & 63, wv = tid >> 6;
  int rowBase = blockIdx.y*128, colBase = blockIdx.x*128;
  int rW = (wv >> 1)*64, cW = (wv & 1)*64;
  int m = lane & 15, q = lane >> 4;
  int rl = lane >> 3, sl = lane & 7;
  floatx4 acc[4][4] = {};
  for (int p = 0; p < 3; p++){
    int aoff = (p == 1) ? 256 : 0;
    int boff = (p == 2) ? 256 : 0;
    for (int k0 = 0; k0 < 256; k0 += 64){
      #pragma unroll
      for (int t4 = 0; t4 < 4; t4++){
        int rloc = wv*32 + t4*8 + rl;
        int g = sl ^ (rloc & 7);
        async16(&As[(wv*32 + t4*8)*64], A + (size_t)(rowBase + rloc)*KS + aoff + k0 + g*8);
        async16(&Bs[(wv*32 + t4*8)*64], B + (size_t)(colBase + rloc)*KS + boff + k0 + g*8);
      }
      __syncthreads();
      #pragma unroll
      for (int kk = 0; kk < 2; kk++){
        short8 af[4], bfr[4];
        #pragma unroll
        for (int i = 0; i < 4; i++){
          int rA = rW + i*16 + m;
          af[i]  = *(const short8*)&As[rA*64 + (((kk*4 + q) ^ (rA & 7))*8)];
          int rB = cW + i*16 + m;
          bfr[i] = *(const short8*)&Bs[rB*64 + (((kk*4 + q) ^ (rB & 7))*8)];
        }
        #pragma unroll
        for (int i = 0; i < 4; i++)
          #pragma unroll
          for (int j = 0; j < 4; j++)
            acc[i][j] = __builtin_amdgcn_mfma_f32_16x16x32_bf16(af[i], bfr[j], acc[i][j], 0, 0, 0);
      }
      __syncthreads();
    }
  }
  float am1 = g_scal[0], am2 = g_scal[1];
  float* __restrict__ outs = out + (size_t)s*NN2;
  #pragma unroll
  for (int i = 0; i < 4; i++){
    #pragma unroll
    for (int j = 0; j < 4; j++){
      int col = colBase + cW + j*16 + m;
      #pragma unroll
      for (int r = 0; r < 4; r++){
        int row = rowBase + rW + i*16 + q*4 + r;
        float val = am1*init[(size_t)row*NVARS + col] + am2*acc[i][j][r];
        if (row == col) val = -__builtin_inff();
        outs[(size_t)row*NVARS + col] = val;
      }
    }
  }
}

// ---------------- pass-1 histogram (standalone streaming pass) --------------
__global__ __launch_bounds__(256) void k_hist1(const float* __restrict__ out){
  int s = blockIdx.z;
  if (!g_state[s][0]) return;
  __shared__ unsigned h[2048];
  int tid = threadIdx.x;
  for (int i = tid; i < 2048; i += 256) h[i] = 0u;
  __syncthreads();
  const float4* p = (const float4*)(out + (size_t)s*NN2);
  int stride = gridDim.x*256;
  for (int i = blockIdx.x*256 + tid; i < NN2/4; i += stride){
    float4 v = p[i];
    float xs[4] = {v.x, v.y, v.z, v.w};
    #pragma unroll
    for (int j = 0; j < 4; j++) atomicAdd(&h[fkey(xs[j]) >> 21], 1u);
  }
  __syncthreads();
  for (int i = tid; i < 2048; i += 256){
    unsigned c = h[i];
    if (c) atomicAdd(&g_hist[s][i], c);
  }
}

// ---------------- shared select helpers ----------------
__device__ void desc_select(unsigned* h, unsigned* sc, int nb, unsigned rank,
                            unsigned* od, unsigned* orem, unsigned* ocnt){
  int tid = threadIdx.x;
  int per = nb >> 8;
  unsigned loc[8];
  unsigned own = 0;
  int base = tid*per;
  for (int j = 0; j < per; j++){ loc[j] = h[base+j]; own += loc[j]; }
  sc[tid] = own;
  __syncthreads();
  for (int off = 1; off < 256; off <<= 1){
    unsigned v = (tid + off < 256) ? sc[tid+off] : 0u;
    __syncthreads();
    sc[tid] += v;
    __syncthreads();
  }
  unsigned acc = sc[tid] - own;  // strictly-higher threads
  for (int j = per-1; j >= 0; j--){
    unsigned c = loc[j];
    if (c && rank > acc && rank <= acc + c){ *od = (unsigned)(base+j); *orem = rank - acc; *ocnt = c; }
    acc += c;
  }
  __syncthreads();
}
__device__ void asc_select(unsigned* h, unsigned* sc, int nb, unsigned rank,
                           unsigned* od, unsigned* orem){
  int tid = threadIdx.x;
  int per = nb >> 8;
  unsigned loc[8];
  unsigned own = 0;
  int base = tid*per;
  for (int j = 0; j < per; j++){ loc[j] = h[base+j]; own += loc[j]; }
  sc[tid] = own;
  __syncthreads();
  for (int off = 1; off < 256; off <<= 1){
    unsigned v = (tid >= off) ? sc[tid-off] : 0u;
    __syncthreads();
    sc[tid] += v;
    __syncthreads();
  }
  unsigned below = sc[tid] - own;
  for (int j = 0; j < per; j++){
    unsigned c = loc[j];
    if (c && rank > below && rank <= below + c){ *od = (unsigned)(base+j); *orem = rank - below; }
    below += c;
  }
  __syncthreads();
}

// ---------------- pass-1 bin select ----------------
__global__ __launch_bounds__(256) void k_select1(){
  int s = blockIdx.x;
  if (!g_state[s][0]) return;
  int tid = threadIdx.x;
  __shared__ unsigned h[2048];
  __shared__ unsigned sc[256];
  __shared__ unsigned sd, srem, scnt;
  for (int i = tid; i < 2048; i += 256) h[i] = g_hist[s][i];
  if (tid == 0){ sd = 0; srem = 1; scnt = 1; }
  __syncthreads();
  desc_select(h, sc, 2048, K_SEL, &sd, &srem, &scnt);
  if (tid == 0){ g_state[s][2] = sd << 21; g_state[s][3] = srem; }
}

// ---------------- compact candidate indices in selected bin ----------------
__global__ __launch_bounds__(256) void k_collect(const float* __restrict__ out){
  int s = blockIdx.z;
  if (!g_state[s][0]) return;
  unsigned pb = g_state[s][2] >> 21;
  const float4* p = (const float4*)(out + (size_t)s*NN2);
  int stride = gridDim.x*256;
  for (int i = blockIdx.x*256 + threadIdx.x; i < NN2/4; i += stride){
    float4 v = p[i];
    float xs[4] = {v.x, v.y, v.z, v.w};
    #pragma unroll
    for (int j = 0; j < 4; j++){
      if ((fkey(xs[j]) >> 21) == pb){
        unsigned pos = atomicAdd(&g_state[s][8], 1u);
        if (pos < CAP) g_cand[s][pos] = (unsigned)(i*4 + j);
      }
    }
  }
}

// ---------------- exact threshold + index tie-break among candidates --------
__global__ __launch_bounds__(256) void k_final(const float* __restrict__ out){
  int s = blockIdx.x;
  if (!g_state[s][0]) return;
  int tid = threadIdx.x;
  unsigned mcnt = g_state[s][8]; if (mcnt > CAP) mcnt = CAP;
  unsigned krem = g_state[s][3];
  unsigned prefix = g_state[s][2];
  const float* outs = out + (size_t)s*NN2;
  __shared__ unsigned h[2048];
  __shared__ unsigned sc[256];
  __shared__ unsigned sd, srem, scnt;
  // phase 1: fkey bits 20..10
  for (int i = tid; i < 2048; i += 256) h[i] = 0u;
  if (tid == 0){ sd = 0; srem = 1; scnt = 1; }
  __syncthreads();
  for (unsigned i = tid; i < mcnt; i += 256){
    unsigned u = fkey(outs[g_cand[s][i]]);
    atomicAdd(&h[(u >> 10) & 0x7FFu], 1u);
  }
  __syncthreads();
  desc_select(h, sc, 2048, krem, &sd, &srem, &scnt);
  unsigned d1 = sd, krem2 = srem;
  __syncthreads();
  // phase 2: fkey bits 9..0
  for (int i = tid; i < 2048; i += 256) h[i] = 0u;
  __syncthreads();
  for (unsigned i = tid; i < mcnt; i += 256){
    unsigned u = fkey(outs[g_cand[s][i]]);
    if (((u >> 10) & 0x7FFu) == d1) atomicAdd(&h[u & 0x3FFu], 1u);
  }
  __syncthreads();
  desc_select(h, sc, 1024, krem2, &sd, &srem, &scnt);
  unsigned d0 = sd, nek = srem, cnteq = scnt;
  __syncthreads();
  unsigned tu = prefix | (d1 << 10) | d0;
  unsigned cutoff = 0x7FFFFFFFu;
  if (nek < cnteq){
    // phase 3: nek-th smallest index, high 11 bits
    for (int i = tid; i < 2048; i += 256) h[i] = 0u;
    __syncthreads();
    for (unsigned i = tid; i < mcnt; i += 256){
      unsigned idx = g_cand[s][i];
      if (fkey(outs[idx]) == tu) atomicAdd(&h[idx >> 11], 1u);
    }
    __syncthreads();
    asc_select(h, sc, 2048, nek, &sd, &srem);
    unsigned dh = sd, j2 = srem;
    __syncthreads();
    // phase 4: low 11 bits
    for (int i = tid; i < 2048; i += 256) h[i] = 0u;
    __syncthreads();
    for (unsigned i = tid; i < mcnt; i += 256){
      unsigned idx = g_cand[s][i];
      if (fkey(outs[idx]) == tu && (idx >> 11) == dh) atomicAdd(&h[idx & 0x7FFu], 1u);
    }
    __syncthreads();
    asc_select(h, sc, 2048, j2, &sd, &srem);
    cutoff = (dh << 11) | sd;
    __syncthreads();
  }
  if (tid == 0){ g_state[s][4] = tu; g_state[s][7] = cutoff; }
}

// ---------------- mask + tanh/relu + eye + normalize + multicast to dups ----
__global__ __launch_bounds__(256) void k_masknorm(float* __restrict__ out){
  int s = blockIdx.y;
  if (!g_state[s][0]) return;
  int r = blockIdx.x;
  int tid = threadIdx.x;
  unsigned tu = g_state[s][4];
  unsigned cutoff = g_state[s][7];
  const float4* rowp = (const float4*)(out + (size_t)s*NN2 + (size_t)r*NVARS);
  unsigned baseIdx = (unsigned)(r*NVARS);
  float4 res[2];
  double lsum = 0.0;
  #pragma unroll
  for (int t = 0; t < 2; t++){
    int c4 = tid + t*256;
    float4 a4 = rowp[c4];
    float av[4] = {a4.x, a4.y, a4.z, a4.w};
    float rv[4];
    #pragma unroll
    for (int j = 0; j < 4; j++){
      int c = c4*4 + j;
      float vv;
      if (c == r) vv = 1.0f;
      else {
        unsigned u = fkey(av[j]);
        bool keep = (u > tu) || (u == tu && (baseIdx + (unsigned)c) <= cutoff);
        vv = keep ? fmaxf(tanhf(av[j]), 0.0f) : 0.0f;
      }
      rv[j] = vv;
      lsum += (double)vv;
    }
    res[t].x = rv[0]; res[t].y = rv[1]; res[t].z = rv[2]; res[t].w = rv[3];
  }
  __shared__ double red[256];
  red[tid] = lsum;
  __syncthreads();
  for (int off = 128; off > 0; off >>= 1){
    if (tid < off) red[tid] += red[tid+off];
    __syncthreads();
  }
  float inv = 1.0f / (float)red[0];
  #pragma unroll
  for (int t = 0; t < 2; t++){
    res[t].x *= inv; res[t].y *= inv; res[t].z *= inv; res[t].w *= inv;
  }
  for (int s2 = 0; s2 < NSLOT; s2++){
    if (g_state[s2][1] == (unsigned)s){
      float4* dst = (float4*)(out + (size_t)s2*NN2 + (size_t)r*NVARS);
      dst[tid]       = res[0];
      dst[tid + 256] = res[1];
    }
  }
}

// ---------------- host launcher ----------------
extern "C" void kernel_launch(void* const* d_in, const int* in_sizes, int n_in,
                              void* d_out, int out_size, void* d_ws, size_t ws_size,
                              hipStream_t stream){
  (void)in_sizes; (void)n_in; (void)d_ws; (void)ws_size; (void)out_size;
  const float* init = (const float*)d_in[0];
  const float* emb1 = (const float*)d_in[1];
  const float* emb2 = (const float*)d_in[2];
  const float* w1   = (const float*)d_in[3];
  const float* b1   = (const float*)d_in[4];
  const float* w2   = (const float*)d_in[5];
  const float* b2   = (const float*)d_in[6];
  const int* tind   = (const int*)d_in[7];
  const int* epoch  = (const int*)d_in[8];
  float* out = (float*)d_out;

  k_prep<<<1, 256, 0, stream>>>(tind, epoch);
  k_split<<<dim3(288, 1, 16), 256, 0, stream>>>(emb1, emb2, w1, w2, tind);
  k_gemm_nv<<<dim3(2, 16, 16), 256, 0, stream>>>(b1, b2, tind);
  k_gemm_s<<<dim3(16, 16, 8), 256, 0, stream>>>(init, out);
  k_hist1<<<dim3(256, 1, 8), 256, 0, stream>>>(out);
  k_select1<<<8, 256, 0, stream>>>();
  k_collect<<<dim3(256, 1, 8), 256, 0, stream>>>(out);
  k_final<<<8, 256, 0, stream>>>(out);
  k_masknorm<<<dim3(2048, 8), 256, 0, stream>>>(out);
}